// Round 1
// baseline (598.312 us; speedup 1.0000x reference)
//
#include <hip/hip_runtime.h>

typedef short s8v __attribute__((ext_vector_type(8)));
typedef float f32x4 __attribute__((ext_vector_type(4)));

#define BM 32
#define KC 64
#define PAD 72   // padded LDS k-stride in bf16 elems: stride 144B -> 2-way bank aliasing (free)

__device__ __forceinline__ unsigned short f2bf(float x) {
    unsigned int u = __float_as_uint(x);
    u += 0x7fffu + ((u >> 16) & 1u);   // RNE
    return (unsigned short)(u >> 16);
}

// C[m][f] = sum_k A[m][k] * B[k][f],  A fp32 [M][lda] row-major,
// Bt bf16 stored transposed [128 f][ldb k].  Split-K via blockIdx.y:
// block handles k range [blockIdx.y*klen, +klen), writes fp32 partial slab
// C + blockIdx.y * M*128.
__global__ __launch_bounds__(256, 2) void gemm_kernel(
    const float* __restrict__ A, int lda,
    const unsigned short* __restrict__ Bt, int ldb,
    float* __restrict__ C, int klen)
{
    __shared__ __align__(16) unsigned short As[2][BM * PAD];    //  9 KB
    __shared__ __align__(16) unsigned short Bs[2][128 * PAD];   // 36 KB  (total 45KB -> 2 blocks/CU)

    const int t    = threadIdx.x;
    const int wave = t >> 6;
    const int lane = t & 63;
    const int quad = lane >> 4;
    const int l16  = lane & 15;

    const int mbase = blockIdx.x * BM;
    const int k0    = blockIdx.y * klen;
    C += (size_t)blockIdx.y * gridDim.x * BM * 128;

    // staging: A chunk 32x64 fp32 (8 consecutive floats / thread),
    //          B chunk 128x64 bf16 (4 rows of 8 bf16 / thread)
    const int ar  = t >> 3;          // 0..31
    const int akg = (t & 7) * 8;     // k offset
    const float*          Ap = A  + (size_t)(mbase + ar) * lda + k0 + akg;
    const unsigned short* Bp = Bt + (size_t)ar * ldb + k0 + akg;

    const int nchunks = klen / KC;

    // ---- prologue: stage chunk 0 into buffer 0 ----
    {
        float4 a0 = *(const float4*)(Ap);
        float4 a1 = *(const float4*)(Ap + 4);
        s8v b0 = *(const s8v*)(Bp);
        s8v b1 = *(const s8v*)(Bp + (size_t)32 * ldb);
        s8v b2 = *(const s8v*)(Bp + (size_t)64 * ldb);
        s8v b3 = *(const s8v*)(Bp + (size_t)96 * ldb);
        s8v av;
        av[0] = (short)f2bf(a0.x); av[1] = (short)f2bf(a0.y);
        av[2] = (short)f2bf(a0.z); av[3] = (short)f2bf(a0.w);
        av[4] = (short)f2bf(a1.x); av[5] = (short)f2bf(a1.y);
        av[6] = (short)f2bf(a1.z); av[7] = (short)f2bf(a1.w);
        *(s8v*)&As[0][ar * PAD + akg] = av;
        *(s8v*)&Bs[0][(ar +  0) * PAD + akg] = b0;
        *(s8v*)&Bs[0][(ar + 32) * PAD + akg] = b1;
        *(s8v*)&Bs[0][(ar + 64) * PAD + akg] = b2;
        *(s8v*)&Bs[0][(ar + 96) * PAD + akg] = b3;
    }
    __syncthreads();

    f32x4 acc00 = {0.f,0.f,0.f,0.f}, acc01 = {0.f,0.f,0.f,0.f};
    f32x4 acc10 = {0.f,0.f,0.f,0.f}, acc11 = {0.f,0.f,0.f,0.f};

    // fragment addresses (bf16 units). A-frag: A[m=l16][k=quad*8+j];
    // B-frag: B[k=quad*8+j][n=l16] -> read row n of Bs[n][k].
    const int arow0 = l16 * PAD;
    const int arow1 = (16 + l16) * PAD;
    const int brow0 = (wave * 32 + l16) * PAD;
    const int brow1 = (wave * 32 + 16 + l16) * PAD;
    const int kq    = quad * 8;

    for (int c = 0; c < nchunks; ++c) {
        const int  cur = c & 1;
        const bool pf  = (c + 1 < nchunks);
        float4 a0, a1; s8v b0, b1, b2, b3;
        if (pf) {
            const size_t o = (size_t)(c + 1) * KC;
            a0 = *(const float4*)(Ap + o);
            a1 = *(const float4*)(Ap + o + 4);
            b0 = *(const s8v*)(Bp + o);
            b1 = *(const s8v*)(Bp + o + (size_t)32 * ldb);
            b2 = *(const s8v*)(Bp + o + (size_t)64 * ldb);
            b3 = *(const s8v*)(Bp + o + (size_t)96 * ldb);
        }
        const unsigned short* as = As[cur];
        const unsigned short* bs = Bs[cur];
        #pragma unroll
        for (int kk = 0; kk < 2; ++kk) {
            const int ko = kk * 32 + kq;
            s8v af0 = *(const s8v*)&as[arow0 + ko];
            s8v af1 = *(const s8v*)&as[arow1 + ko];
            s8v bg0 = *(const s8v*)&bs[brow0 + ko];
            s8v bg1 = *(const s8v*)&bs[brow1 + ko];
            acc00 = __builtin_amdgcn_mfma_f32_16x16x32_bf16(af0, bg0, acc00, 0, 0, 0);
            acc01 = __builtin_amdgcn_mfma_f32_16x16x32_bf16(af0, bg1, acc01, 0, 0, 0);
            acc10 = __builtin_amdgcn_mfma_f32_16x16x32_bf16(af1, bg0, acc10, 0, 0, 0);
            acc11 = __builtin_amdgcn_mfma_f32_16x16x32_bf16(af1, bg1, acc11, 0, 0, 0);
        }
        if (pf) {
            const int nb = cur ^ 1;
            s8v av;
            av[0] = (short)f2bf(a0.x); av[1] = (short)f2bf(a0.y);
            av[2] = (short)f2bf(a0.z); av[3] = (short)f2bf(a0.w);
            av[4] = (short)f2bf(a1.x); av[5] = (short)f2bf(a1.y);
            av[6] = (short)f2bf(a1.z); av[7] = (short)f2bf(a1.w);
            *(s8v*)&As[nb][ar * PAD + akg] = av;
            *(s8v*)&Bs[nb][(ar +  0) * PAD + akg] = b0;
            *(s8v*)&Bs[nb][(ar + 32) * PAD + akg] = b1;
            *(s8v*)&Bs[nb][(ar + 64) * PAD + akg] = b2;
            *(s8v*)&Bs[nb][(ar + 96) * PAD + akg] = b3;
        }
        __syncthreads();
    }

    // epilogue: C/D layout col = lane&15, row = quad*4 + reg
    const int col = wave * 32 + l16;
    const int row = mbase + quad * 4;
    #pragma unroll
    for (int i = 0; i < 4; ++i) {
        C[(size_t)(row + i)      * 128 + col]      = acc00[i];
        C[(size_t)(row + i)      * 128 + col + 16] = acc01[i];
        C[(size_t)(row + 16 + i) * 128 + col]      = acc10[i];
        C[(size_t)(row + 16 + i) * 128 + col + 16] = acc11[i];
    }
}

// Transpose+convert: a (and optional b) are [nrows][128] fp32.
// out[f][k] = bf16( scale(k) * (a[k][f] (+ b[k][f])) ),  out row stride = nrows.
// mode==1: add b and apply scale(k) = sum_j dl[j][k]^2 * ft[j][k].
__global__ __launch_bounds__(256) void tkern(
    const float* __restrict__ a, const float* __restrict__ b,
    const float* __restrict__ dl, const float* __restrict__ ft,
    unsigned short* __restrict__ out, int nrows, int mode)
{
    __shared__ __align__(16) unsigned short L[128 * PAD];
    const int t    = threadIdx.x;
    const int kb   = blockIdx.x * 64;
    const int kloc = t >> 2;
    const int fseg = (t & 3) * 32;
    const int k    = kb + kloc;

    float s = 1.0f;
    if (mode) {
        float s0 = 0.f;
        #pragma unroll
        for (int j = 0; j < 3; ++j) {
            float d = dl[(size_t)j * nrows + k];
            s0 += d * d * ft[(size_t)j * nrows + k];
        }
        s = s0;
    }
    const float* ap = a + (size_t)k * 128 + fseg;
    const float* bp = b + (size_t)k * 128 + fseg;   // only deref'd when mode
    #pragma unroll
    for (int i = 0; i < 8; ++i) {
        float4 v = *(const float4*)(ap + i * 4);
        if (mode) {
            float4 w = *(const float4*)(bp + i * 4);
            v.x += w.x; v.y += w.y; v.z += w.z; v.w += w.w;
        }
        const int fb = fseg + i * 4;
        L[(fb + 0) * PAD + kloc] = f2bf(v.x * s);
        L[(fb + 1) * PAD + kloc] = f2bf(v.y * s);
        L[(fb + 2) * PAD + kloc] = f2bf(v.z * s);
        L[(fb + 3) * PAD + kloc] = f2bf(v.w * s);
    }
    __syncthreads();
    const int f    = t >> 1;
    const int half = (t & 1) * 32;
    unsigned short* op = out + (size_t)f * nrows + kb + half;
    #pragma unroll
    for (int i = 0; i < 4; ++i) {
        *(s8v*)(op + i * 8) = *(const s8v*)&L[f * PAD + half + i * 8];
    }
}

__global__ __launch_bounds__(256) void addbias_kernel(
    const float* __restrict__ p0, const float* __restrict__ p1,
    const float* __restrict__ bias, float* __restrict__ out)
{
    const size_t e = ((size_t)blockIdx.x * 256 + threadIdx.x) * 4;
    float4 x = *(const float4*)(p0 + e);
    float4 y = *(const float4*)(p1 + e);
    float4 bb = *(const float4*)(bias + (e & 127));
    float4 r;
    r.x = x.x + y.x + bb.x;
    r.y = x.y + y.y + bb.y;
    r.z = x.z + y.z + bb.z;
    r.w = x.w + y.w + bb.w;
    *(float4*)(out + e) = r;
}

extern "C" void kernel_launch(void* const* d_in, const int* in_sizes, int n_in,
                              void* d_out, int out_size, void* d_ws, size_t ws_size,
                              hipStream_t stream)
{
    const float* x  = (const float*)d_in[0];   // [8192][128]
    const float* dl = (const float*)d_in[1];   // [3][8192]
    const float* U  = (const float*)d_in[2];   // [8192][8192]
    const float* Vt = (const float*)d_in[3];   // [8192][8192]
    const float* W  = (const float*)d_in[4];   // [128][128]
    const float* ft = (const float*)d_in[5];   // [3][8192]
    const float* bs = (const float*)d_in[6];   // [128]
    float* out = (float*)d_out;

    const int N = 8192, F = 128;
    char* ws = (char*)d_ws;
    unsigned short* Wt  = (unsigned short*)(ws);                           // 32KB (64KB reserved)
    unsigned short* xwt = (unsigned short*)(ws + (64 << 10));              // 2MB  bf16 [128][8192]
    unsigned short* yt  = (unsigned short*)(ws + (64 << 10) + (2 << 20));  // 2MB  bf16 [128][8192]
    float* bufA = (float*)(ws + (64 << 10) + (4 << 20));                   // 8MB: xw fp32, later out partials
    float* bufB = (float*)(ws + (64 << 10) + (12 << 20));                  // 8MB: y partials [2][8192][128]

    // T0: Wt[f][c] = bf16(W[c][f])
    tkern<<<dim3(F / 64), 256, 0, stream>>>(W, nullptr, nullptr, nullptr, Wt, F, 0);
    // G1: xw = x @ W   (A = x [N][128] fp32, B = Wt)
    gemm_kernel<<<dim3(N / BM, 1), 256, 0, stream>>>(x, F, Wt, F, bufA, F);
    // T1: xwt[f][n] = bf16(xw[n][f])
    tkern<<<dim3(N / 64), 256, 0, stream>>>(bufA, nullptr, nullptr, nullptr, xwt, N, 0);
    // G2: y_part[s] = Vt @ xw  (split-K 2)
    gemm_kernel<<<dim3(N / BM, 2), 256, 0, stream>>>(Vt, N, xwt, N, bufB, N / 2);
    // T2: yt[f][k] = bf16( scale(k) * (y0[k][f] + y1[k][f]) )
    tkern<<<dim3(N / 64), 256, 0, stream>>>(bufB, bufB + (size_t)N * F, dl, ft, yt, N, 1);
    // G3: out_part[s] = U @ y  (split-K 2)
    gemm_kernel<<<dim3(N / BM, 2), 256, 0, stream>>>(U, N, yt, N, bufA, N / 2);
    // T3: out = p0 + p1 + bias
    addbias_kernel<<<dim3((N * F) / (256 * 4)), 256, 0, stream>>>(
        bufA, bufA + (size_t)N * F, bs, out);
}